// Round 13
// baseline (1028.905 us; speedup 1.0000x reference)
//
#include <hip/hip_runtime.h>
#include <hip/hip_bf16.h>

#define LL 12
#define BB 32
#define SS 197
#define DV 768
#define DD 512
#define CC 48
#define VV 49
#define LOSS_DEN 786432.0f

typedef unsigned short u16;
typedef unsigned int u32;
using bf16x8 = __attribute__((ext_vector_type(8))) __bf16;
using f32x4 = __attribute__((ext_vector_type(4))) float;
using u16x8 = __attribute__((ext_vector_type(8))) u16;
using u16x4 = __attribute__((ext_vector_type(4))) u16;

__device__ __forceinline__ u16 bf16h(float x) {
    u32 u = __builtin_bit_cast(u32, x);
    return (u16)((u + 0x7FFFu + ((u >> 16) & 1u)) >> 16);
}
__device__ __forceinline__ float bf2f(u16 h) {
    u32 u = ((u32)h) << 16;
    return __builtin_bit_cast(float, u);
}
__device__ __forceinline__ f32x4 mfma16(bf16x8 a, bf16x8 b, f32x4 c) {
    return __builtin_amdgcn_mfma_f32_16x16x32_bf16(a, b, c, 0, 0, 0);
}
__device__ __forceinline__ void gl_lds16(const void* g, void* s) {
    __builtin_amdgcn_global_load_lds((const __attribute__((address_space(1))) u32*)g,
                                     (__attribute__((address_space(3))) u32*)s, 16, 0, 0);
}

#define NLW (512 * 768)
#define NGW (512 * 1536)
#define NUW (512 * 1024)
// mega_pre segments
#define CTX_BLKS 48
#define WCOMB_BLKS 96      // per array (8 x 12 of 64x64, M=512 N=768)
#define BIAS_BLKS 1
#define POOL2_BLKS (LL * BB * 2)                  // 768
#define WSPLIT4_BLKS ((NLW + NGW + NUW) / 1024)   // 1664
#define INITQ8_BLKS ((BB * CC * DD) / 2048)       // 384

// ---------------------------------------------------------------------------
// f32 64x64 NT tile: C[m,n] = sum_k A[m,k]*W[n*wstride+k] + bias[n]; C f32, ldc=512
__device__ __forceinline__ void gemm_f32_tile(const float* __restrict__ A, int lda,
                                              const float* __restrict__ W, int wstride, int K,
                                              const float* __restrict__ bias,
                                              float* __restrict__ Cout,
                                              int m0, int n0, int t, float* AsB, float* BsB) {
    float (*As)[65] = (float(*)[65])AsB;
    float (*Bs)[65] = (float(*)[65])BsB;
    int r = t >> 2;
    int kc = (t & 3) * 8;
    int tx = t & 15, ty = t >> 4;
    float acc[4][4] = {};
    for (int k0 = 0; k0 < K; k0 += 32) {
        const float4* pa = (const float4*)(A + (size_t)(m0 + r) * lda + k0 + kc);
        float4 a0 = pa[0], a1 = pa[1];
        const float4* pw = (const float4*)(W + (size_t)(n0 + r) * wstride + k0 + kc);
        float4 w0 = pw[0], w1 = pw[1];
        As[kc + 0][r] = a0.x; As[kc + 1][r] = a0.y; As[kc + 2][r] = a0.z; As[kc + 3][r] = a0.w;
        As[kc + 4][r] = a1.x; As[kc + 5][r] = a1.y; As[kc + 6][r] = a1.z; As[kc + 7][r] = a1.w;
        Bs[kc + 0][r] = w0.x; Bs[kc + 1][r] = w0.y; Bs[kc + 2][r] = w0.z; Bs[kc + 3][r] = w0.w;
        Bs[kc + 4][r] = w1.x; Bs[kc + 5][r] = w1.y; Bs[kc + 6][r] = w1.z; Bs[kc + 7][r] = w1.w;
        __syncthreads();
#pragma unroll
        for (int kk = 0; kk < 32; ++kk) {
            float a[4], b[4];
#pragma unroll
            for (int i = 0; i < 4; ++i) { a[i] = As[kk][ty * 4 + i]; b[i] = Bs[kk][tx * 4 + i]; }
#pragma unroll
            for (int i = 0; i < 4; ++i)
#pragma unroll
                for (int j = 0; j < 4; ++j) acc[i][j] += a[i] * b[j];
        }
        __syncthreads();
    }
#pragma unroll
    for (int i = 0; i < 4; ++i) {
        int m = m0 + ty * 4 + i;
#pragma unroll
        for (int j = 0; j < 4; ++j) {
            int n = n0 + tx * 4 + j;
            Cout[(size_t)m * DD + n] = acc[i][j] + (bias ? bias[n] : 0.0f);
        }
    }
}

// ---------------------------------------------------------------------------
// f32 64x64 NN tile: C[m,j] = sum_k A[m*lda+k]*B[k*ldb+j]; output bf16-hi, ldc.
__device__ __forceinline__ void gemm_f32_nn(const float* __restrict__ A, int lda,
                                            const float* __restrict__ B, int ldb, int K,
                                            u16* __restrict__ Cbf, int ldc,
                                            int m0, int n0, int t, float* AsB, float* BsB) {
    float (*As)[65] = (float(*)[65])AsB;
    float (*Bs)[68] = (float(*)[68])BsB;
    int tx = t & 15, ty = t >> 4;
    float acc[4][4] = {};
    for (int k0 = 0; k0 < K; k0 += 32) {
        {
            int r = t >> 2, kc = (t & 3) * 8;
            const float4* pa = (const float4*)(A + (size_t)(m0 + r) * lda + k0 + kc);
            float4 a0 = pa[0], a1 = pa[1];
            As[kc + 0][r] = a0.x; As[kc + 1][r] = a0.y; As[kc + 2][r] = a0.z; As[kc + 3][r] = a0.w;
            As[kc + 4][r] = a1.x; As[kc + 5][r] = a1.y; As[kc + 6][r] = a1.z; As[kc + 7][r] = a1.w;
        }
        {
            int kr = t >> 3, jc = (t & 7) * 8;
            const float4* pb = (const float4*)(B + (size_t)(k0 + kr) * ldb + n0 + jc);
            float4 b0 = pb[0], b1 = pb[1];
            Bs[kr][jc + 0] = b0.x; Bs[kr][jc + 1] = b0.y; Bs[kr][jc + 2] = b0.z; Bs[kr][jc + 3] = b0.w;
            Bs[kr][jc + 4] = b1.x; Bs[kr][jc + 5] = b1.y; Bs[kr][jc + 6] = b1.z; Bs[kr][jc + 7] = b1.w;
        }
        __syncthreads();
#pragma unroll
        for (int kk = 0; kk < 32; ++kk) {
            float a[4], b[4];
#pragma unroll
            for (int i = 0; i < 4; ++i) { a[i] = As[kk][ty * 4 + i]; b[i] = Bs[kk][tx * 4 + i]; }
#pragma unroll
            for (int i = 0; i < 4; ++i)
#pragma unroll
                for (int j = 0; j < 4; ++j) acc[i][j] += a[i] * b[j];
        }
        __syncthreads();
    }
#pragma unroll
    for (int i = 0; i < 4; ++i)
#pragma unroll
        for (int j = 0; j < 4; ++j)
            Cbf[(size_t)(m0 + ty * 4 + i) * ldc + n0 + tx * 4 + j] = bf16h(acc[i][j]);
}

// ---------------------------------------------------------------------------
// Merged precompute.
__global__ __launch_bounds__(256) void mega_pre(const float* __restrict__ feats,
                                                const float* __restrict__ Wl,
                                                const float* __restrict__ Wg,
                                                const float* __restrict__ Wu,
                                                const float* __restrict__ Wp,
                                                const float* __restrict__ bl,
                                                const float* __restrict__ bg,
                                                const float* __restrict__ buv,
                                                const float* __restrict__ ce,
                                                u16* __restrict__ Xh, u16* __restrict__ Xl,
                                                u16* Wlh, u16* Wll, u16* Wgh, u16* Wuh,
                                                u16* Wcg, u16* Wcu,
                                                float* __restrict__ bg2, float* __restrict__ bu2,
                                                u16* __restrict__ qh, u16* __restrict__ ql,
                                                float* __restrict__ loss,
                                                float* __restrict__ ctx) {
    __shared__ float smf[32 * 65 + 32 * 68];
    int bid = blockIdx.x;
    int t = threadIdx.x;
    if (bid < CTX_BLKS) {
        gemm_f32_tile(feats, SS * DV, Wp, DV, DV, nullptr, ctx,
                      (bid >> 3) * 64, (bid & 7) * 64, t, smf, smf + 32 * 65);
    } else if (bid < CTX_BLKS + 2 * WCOMB_BLKS) {
        int b2 = bid - CTX_BLKS;
        int which = b2 >= WCOMB_BLKS;
        int b3 = b2 - which * WCOMB_BLKS;
        int m0 = (b3 / 12) * 64, n0 = (b3 % 12) * 64;
        if (which == 0)
            gemm_f32_nn(Wg, 1536, Wl, DV, 512, Wcg, DV, m0, n0, t, smf, smf + 32 * 65);
        else
            gemm_f32_nn(Wu, 1024, Wl, DV, 512, Wcu, DV, m0, n0, t, smf, smf + 32 * 65);
    } else if (bid < CTX_BLKS + 2 * WCOMB_BLKS + BIAS_BLKS) {
        for (int n = t; n < 512; n += 256) {
            float sg = bg[n], su = buv[n];
            for (int k = 0; k < 512; ++k) {
                float blv = bl[k];
                sg += Wg[(size_t)n * 1536 + k] * blv;
                su += Wu[(size_t)n * 1024 + k] * blv;
            }
            bg2[n] = sg;
            bu2[n] = su;
        }
    } else if (bid < CTX_BLKS + 2 * WCOMB_BLKS + BIAS_BLKS + POOL2_BLKS) {
        if (t >= 192) return;
        int pb = bid - CTX_BLKS - 2 * WCOMB_BLKS - BIAS_BLKS;
        int lb = pb >> 1, half = pb & 1;
        const float4* fb = (const float4*)(feats + (size_t)lb * SS * DV);
        size_t xbase = (size_t)lb * VV * DV + 4 * t;
        if (half == 0) {
            float4 c = fb[t];
            float cv[4] = {c.x, c.y, c.z, c.w};
            u16x4 hh, ll2;
#pragma unroll
            for (int j = 0; j < 4; ++j) {
                u16 h = bf16h(cv[j]);
                hh[j] = h;
                ll2[j] = bf16h(cv[j] - bf2f(h));
            }
            *(u16x4*)(Xh + xbase) = hh;
            *(u16x4*)(Xl + xbase) = ll2;
        }
        int ib0 = half * 24, ib1 = ib0 + 24;
        for (int i = ib0; i < ib1; ++i) {
            int s = (i * 196) / 48;
            int e = ((i + 1) * 196 + 47) / 48;
            float4 acc = {0.f, 0.f, 0.f, 0.f};
            for (int j = s; j < e; ++j) {
                float4 v = fb[(size_t)(1 + j) * 192 + t];
                acc.x += v.x; acc.y += v.y; acc.z += v.z; acc.w += v.w;
            }
            float inv = 1.0f / (float)(e - s);
            float av[4] = {acc.x * inv, acc.y * inv, acc.z * inv, acc.w * inv};
            u16x4 hh, ll2;
#pragma unroll
            for (int j = 0; j < 4; ++j) {
                u16 h = bf16h(av[j]);
                hh[j] = h;
                ll2[j] = bf16h(av[j] - bf2f(h));
            }
            size_t o = xbase + (size_t)(1 + i) * DV;
            *(u16x4*)(Xh + o) = hh;
            *(u16x4*)(Xl + o) = ll2;
        }
    } else if (bid < CTX_BLKS + 2 * WCOMB_BLKS + BIAS_BLKS + POOL2_BLKS + WSPLIT4_BLKS) {
        int i = ((bid - CTX_BLKS - 2 * WCOMB_BLKS - BIAS_BLKS - POOL2_BLKS) * 256 + t) * 4;
        float4 v;
        u16 *ph, *pl = nullptr;
        int j;
        if (i < NLW) { v = *(const float4*)(Wl + i); ph = Wlh; pl = Wll; j = i; }
        else if (i < NLW + NGW) { j = i - NLW; v = *(const float4*)(Wg + j); ph = Wgh; }
        else { j = i - NLW - NGW; v = *(const float4*)(Wu + j); ph = Wuh; }
        float vv[4] = {v.x, v.y, v.z, v.w};
        u16x4 hh, ll2;
#pragma unroll
        for (int k = 0; k < 4; ++k) {
            u16 h = bf16h(vv[k]);
            hh[k] = h;
            ll2[k] = bf16h(vv[k] - bf2f(h));
        }
        *(u16x4*)(ph + j) = hh;
        if (pl) *(u16x4*)(pl + j) = ll2;
    } else {
        int i8 = ((bid - CTX_BLKS - 2 * WCOMB_BLKS - BIAS_BLKS - POOL2_BLKS - WSPLIT4_BLKS) * 256 + t) * 8;
        int src = i8 % (CC * DD);
        float4 a = *(const float4*)(ce + src);
        float4 b2 = *(const float4*)(ce + src + 4);
        float vv[8] = {a.x, a.y, a.z, a.w, b2.x, b2.y, b2.z, b2.w};
        u16x8 hh, ll2;
#pragma unroll
        for (int k = 0; k < 8; ++k) {
            u16 h = bf16h(vv[k]);
            hh[k] = h;
            ll2[k] = bf16h(vv[k] - bf2f(h));
        }
        *(u16x8*)(qh + i8) = hh;
        *(u16x8*)(ql + i8) = ll2;
        if (i8 == 0) loss[0] = 0.0f;
    }
}

// ---------------------------------------------------------------------------
// Big GEMM launch: [0,1176) vt x3 -> f32; [1176,2352) VG x1; [2352,3528) VU x1;
// [3528,3576) Cg f32 (bias bg2).
__global__ __launch_bounds__(256, 2) void big_gemm(const u16* __restrict__ Xh, const u16* __restrict__ Xl,
                                                   const u16* __restrict__ Wh, const u16* __restrict__ Wl,
                                                   const float* __restrict__ bias,
                                                   float* __restrict__ vtf,
                                                   const u16* __restrict__ Wcg, const u16* __restrict__ Wcu,
                                                   float* __restrict__ VG, float* __restrict__ VU,
                                                   const float* __restrict__ ctx,
                                                   const float* __restrict__ Wg,
                                                   const float* __restrict__ bg2,
                                                   float* __restrict__ Cg) {
    __shared__ u16 sm[24576];
    int tid = threadIdx.x;
    if (blockIdx.x >= 3528) {
        int b2 = blockIdx.x - 3528;
        gemm_f32_tile(ctx, DD, Wg + 1024, 1536, DD, bg2, Cg,
                      (b2 >> 3) * 64, (b2 & 7) * 64, tid, (float*)sm, (float*)sm + 32 * 65);
        return;
    }
    int sub = blockIdx.x / 1176;
    int i = blockIdx.x % 1176;
    int w = tid >> 6, l = tid & 63, lr = l & 15, ls = l >> 4;
    int m, n;
    if (i < 1152) { int a = i >> 6, r2 = i & 63; m = 8 * a + (r2 & 7); n = r2 >> 3; }
    else { int j = i - 1152; m = 144 + (j >> 3); n = j & 7; }
    int m0 = m * 128, n0 = n * 64;
    f32x4 acc[2][4];
#pragma unroll
    for (int ii = 0; ii < 2; ++ii)
#pragma unroll
        for (int j = 0; j < 4; ++j) acc[ii][j] = f32x4{0.f, 0.f, 0.f, 0.f};

    if (sub == 0) {
        auto stage = [&](u16* dst, int k0) {
#pragma unroll
            for (int is = 0; is < 6; ++is) {
                int q = is * 256 + tid;
                const u16* src;
                int off;
                if (is < 2)      { int qr = q;        int row = qr >> 2, sl = qr & 3; src = Xh + (size_t)(m0 + row) * DV + k0 + ((sl ^ ((row >> 1) & 3)) << 3); off = qr * 8; }
                else if (is < 4) { int qr = q - 512;  int row = qr >> 2, sl = qr & 3; src = Xl + (size_t)(m0 + row) * DV + k0 + ((sl ^ ((row >> 1) & 3)) << 3); off = 4096 + qr * 8; }
                else if (is < 5) { int qr = q - 1024; int row = qr >> 2, sl = qr & 3; src = Wh + (size_t)(n0 + row) * DV + k0 + ((sl ^ ((row >> 1) & 3)) << 3); off = 8192 + qr * 8; }
                else             { int qr = q - 1280; int row = qr >> 2, sl = qr & 3; src = Wl + (size_t)(n0 + row) * DV + k0 + ((sl ^ ((row >> 1) & 3)) << 3); off = 10240 + qr * 8; }
                gl_lds16(src, dst + off);
            }
        };
        stage(sm, 0);
        __syncthreads();
        for (int t = 0; t < 24; ++t) {
            u16* cur = sm + ((t & 1) ? 12288 : 0);
            if (t + 1 < 24) stage(sm + ((t & 1) ? 0 : 12288), (t + 1) * 32);
            bf16x8 ah[2], al2[2], bh[4], bl2[4];
#pragma unroll
            for (int rf = 0; rf < 2; ++rf) {
                int row = 32 * w + 16 * rf + lr;
                int ro = row * 32 + ((ls ^ ((row >> 1) & 3)) << 3);
                ah[rf] = *(const bf16x8*)(cur + ro);
                al2[rf] = *(const bf16x8*)(cur + 4096 + ro);
            }
#pragma unroll
            for (int cf = 0; cf < 4; ++cf) {
                int nn = 16 * cf + lr;
                int no = nn * 32 + ((ls ^ ((nn >> 1) & 3)) << 3);
                bh[cf] = *(const bf16x8*)(cur + 8192 + no);
                bl2[cf] = *(const bf16x8*)(cur + 10240 + no);
            }
#pragma unroll
            for (int rf = 0; rf < 2; ++rf)
#pragma unroll
                for (int cf = 0; cf < 4; ++cf) {
                    acc[rf][cf] = mfma16(ah[rf], bh[cf], acc[rf][cf]);
                    acc[rf][cf] = mfma16(ah[rf], bl2[cf], acc[rf][cf]);
                    acc[rf][cf] = mfma16(al2[rf], bh[cf], acc[rf][cf]);
                }
            __syncthreads();
        }
#pragma unroll
        for (int rf = 0; rf < 2; ++rf)
#pragma unroll
            for (int cf = 0; cf < 4; ++cf)
#pragma unroll
                for (int r = 0; r < 4; ++r) {
                    int row = m0 + 32 * w + 16 * rf + 4 * ls + r;
                    int col = n0 + 16 * cf + lr;
                    vtf[(size_t)row * DD + col] = acc[rf][cf][r] + bias[col];
                }
    } else {
        const u16* Wc = (sub == 1) ? Wcg : Wcu;
        float* Out = (sub == 1) ? VG : VU;
        auto stage = [&](u16* dst, int k0) {
#pragma unroll
            for (int is = 0; is < 2; ++is) {
                int q = is * 256 + tid;
                int row = q >> 2, sl = q & 3;
                gl_lds16(Xh + (size_t)(m0 + row) * DV + k0 + ((sl ^ ((row >> 1) & 3)) << 3), dst + q * 8);
            }
            {
                int row = tid >> 2, sl = tid & 3;
                gl_lds16(Wc + (size_t)(n0 + row) * DV + k0 + ((sl ^ ((row >> 1) & 3)) << 3), dst + 4096 + tid * 8);
            }
        };
        stage(sm, 0);
        __syncthreads();
        for (int t = 0; t < 24; ++t) {
            u16* cur = sm + (t & 1) * 6144;
            if (t + 1 < 24) stage(sm + ((t + 1) & 1) * 6144, (t + 1) * 32);
            bf16x8 ah[2], bh[4];
#pragma unroll
            for (int rf = 0; rf < 2; ++rf) {
                int row = 32 * w + 16 * rf + lr;
                ah[rf] = *(const bf16x8*)(cur + row * 32 + ((ls ^ ((row >> 1) & 3)) << 3));
            }
#pragma unroll
            for (int cf = 0; cf < 4; ++cf) {
                int nn = 16 * cf + lr;
                bh[cf] = *(const bf16x8*)(cur + 4096 + nn * 32 + ((ls ^ ((nn >> 1) & 3)) << 3));
            }
#pragma unroll
            for (int rf = 0; rf < 2; ++rf)
#pragma unroll
                for (int cf = 0; cf < 4; ++cf)
                    acc[rf][cf] = mfma16(ah[rf], bh[cf], acc[rf][cf]);
            __syncthreads();
        }
#pragma unroll
        for (int rf = 0; rf < 2; ++rf)
#pragma unroll
            for (int cf = 0; cf < 4; ++cf)
#pragma unroll
                for (int r = 0; r < 4; ++r) {
                    int row = m0 + 32 * w + 16 * rf + 4 * ls + r;
                    int col = n0 + 16 * cf + lr;
                    Out[(size_t)row * DD + col] = acc[rf][cf][r];
                }
    }
}

// ---------------------------------------------------------------------------
// Per-layer: blocks 0..191 attention (+q reconstruct/write, gp outputs);
// blocks 192..575: q-part GEMM (A reconstructed into LDS).
__global__ __launch_bounds__(256, 2) void layer_step(
    const u16* __restrict__ qph, const u16* __restrict__ qpl,
    const float* __restrict__ gpgP, const float* __restrict__ gpuP,
    const float* __restrict__ qgP, const float* __restrict__ quP,
    const float* __restrict__ vtL, const float* __restrict__ vgL, const float* __restrict__ vuL,
    const float* __restrict__ CgL, const float* __restrict__ bu2,
    float* __restrict__ fcur, const float* __restrict__ fprev, float* __restrict__ loss,
    int do_loss, int first, int last,
    u16* __restrict__ qoh, u16* __restrict__ qol,
    float* __restrict__ gpgO, float* __restrict__ gpuO,
    const u16* __restrict__ Wgh, const u16* __restrict__ Wuh,
    float* __restrict__ qgO, float* __restrict__ quO) {
    __shared__ u16 sm[32768];
    int tid = threadIdx.x;

    auto recon8 = [&](size_t o, float out[8]) {
        u16x8 ph = *(const u16x8*)(qph + o), pl = *(const u16x8*)(qpl + o);
        if (first) {
#pragma unroll
            for (int j = 0; j < 8; ++j) out[j] = bf2f(ph[j]) + bf2f(pl[j]);
        } else {
            float4 g0 = *(const float4*)(gpgP + o), g1 = *(const float4*)(gpgP + o + 4);
            float4 u0 = *(const float4*)(gpuP + o), u1 = *(const float4*)(gpuP + o + 4);
            float4 a0 = *(const float4*)(qgP + o), a1 = *(const float4*)(qgP + o + 4);
            float4 b0 = *(const float4*)(quP + o), b1 = *(const float4*)(quP + o + 4);
            float gg[8] = {g0.x, g0.y, g0.z, g0.w, g1.x, g1.y, g1.z, g1.w};
            float uu[8] = {u0.x, u0.y, u0.z, u0.w, u1.x, u1.y, u1.z, u1.w};
            float ag[8] = {a0.x, a0.y, a0.z, a0.w, a1.x, a1.y, a1.z, a1.w};
            float bb[8] = {b0.x, b0.y, b0.z, b0.w, b1.x, b1.y, b1.z, b1.w};
#pragma unroll
            for (int j = 0; j < 8; ++j) {
                float g = 1.0f / (1.0f + __expf(-(gg[j] + ag[j])));
                float u = tanhf(uu[j] + bb[j]);
                float qp = bf2f(ph[j]) + bf2f(pl[j]);
                out[j] = g * qp + (1.0f - g) * u;
            }
        }
    };

    if (blockIdx.x < 192) {
        // ---------------- attention ----------------
        int d = blockIdx.x;
        int xcd = d & 7, tt = d >> 3;
        int b = (tt / 6) * 8 + xcd, rg = tt % 6;
        int wv = tid >> 6, lane = tid & 63;
        int r0 = b * CC + rg * 8 + wv * 2;
        size_t o0 = (size_t)r0 * DD + lane * 8;
        float q0v[8], q1v[8];
        recon8(o0, q0v);
        recon8(o0 + DD, q1v);
        if (!last) {
            u16x8 h0, l0, h1, l1;
#pragma unroll
            for (int j = 0; j < 8; ++j) {
                u16 h = bf16h(q0v[j]);
                h0[j] = h;
                l0[j] = bf16h(q0v[j] - bf2f(h));
                u16 h2 = bf16h(q1v[j]);
                h1[j] = h2;
                l1[j] = bf16h(q1v[j] - bf2f(h2));
            }
            *(u16x8*)(qoh + o0) = h0;
            *(u16x8*)(qol + o0) = l0;
            *(u16x8*)(qoh + o0 + DD) = h1;
            *(u16x8*)(qol + o0 + DD) = l1;
        }
        const float* vf = vtL + (size_t)b * VV * DD + lane * 8;
        const float* gf = vgL + (size_t)b * VV * DD + lane * 8;
        const float* uf = vuL + (size_t)b * VV * DD + lane * 8;
        float m0 = -3e38f, m1 = -3e38f, s0 = 0.f, s1 = 0.f;
        float af0[8] = {}, af1[8] = {}, ag0[8] = {}, ag1[8] = {}, au0[8] = {}, au1[8] = {};
        for (int v = 0; v < VV; ++v) {
            float4 r0v = *(const float4*)(vf + (size_t)v * DD);
            float4 r1v = *(const float4*)(vf + (size_t)v * DD + 4);
            float rv[8] = {r0v.x, r0v.y, r0v.z, r0v.w, r1v.x, r1v.y, r1v.z, r1v.w};
            float p0 = 0.f, p1 = 0.f;
#pragma unroll
            for (int j = 0; j < 8; ++j) { p0 += q0v[j] * rv[j]; p1 += q1v[j] * rv[j]; }
#pragma unroll
            for (int off = 32; off > 0; off >>= 1) { p0 += __shfl_xor(p0, off); p1 += __shfl_xor(p1, off); }
            float nm0 = fmaxf(m0, p0);
            float sc0 = __expf(m0 - nm0), w0 = __expf(p0 - nm0);
            s0 = s0 * sc0 + w0;
            float nm1 = fmaxf(m1, p1);
            float sc1 = __expf(m1 - nm1), w1 = __expf(p1 - nm1);
            s1 = s1 * sc1 + w1;
            if (!last) {
                float4 gv0 = *(const float4*)(gf + (size_t)v * DD);
                float4 gv1 = *(const float4*)(gf + (size_t)v * DD + 4);
                float4 uv0 = *(const float4*)(uf + (size_t)v * DD);
                float4 uv1 = *(const float4*)(uf + (size_t)v * DD + 4);
                float gv[8] = {gv0.x, gv0.y, gv0.z, gv0.w, gv1.x, gv1.y, gv1.z, gv1.w};
                float uv[8] = {uv0.x, uv0.y, uv0.z, uv0.w, uv1.x, uv1.y, uv1.z, uv1.w};
#pragma unroll
                for (int j = 0; j < 8; ++j) {
                    af0[j] = af0[j] * sc0 + w0 * rv[j];
                    af1[j] = af1[j] * sc1 + w1 * rv[j];
                    ag0[j] = ag0[j] * sc0 + w0 * gv[j];
                    ag1[j] = ag1[j] * sc1 + w1 * gv[j];
                    au0[j] = au0[j] * sc0 + w0 * uv[j];
                    au1[j] = au1[j] * sc1 + w1 * uv[j];
                }
            } else {
#pragma unroll
                for (int j = 0; j < 8; ++j) {
                    af0[j] = af0[j] * sc0 + w0 * rv[j];
                    af1[j] = af1[j] * sc1 + w1 * rv[j];
                }
            }
            m0 = nm0;
            m1 = nm1;
        }
        float inv0 = 1.0f / s0, inv1 = 1.0f / s1;
        float f0v[8], f1v[8];
#pragma unroll
        for (int j = 0; j < 8; ++j) { f0v[j] = af0[j] * inv0; f1v[j] = af1[j] * inv1; }
        *(float4*)(fcur + o0) = float4{f0v[0], f0v[1], f0v[2], f0v[3]};
        *(float4*)(fcur + o0 + 4) = float4{f0v[4], f0v[5], f0v[6], f0v[7]};
        *(float4*)(fcur + o0 + DD) = float4{f1v[0], f1v[1], f1v[2], f1v[3]};
        *(float4*)(fcur + o0 + DD + 4) = float4{f1v[4], f1v[5], f1v[6], f1v[7]};
        if (do_loss) {
            float d2 = 0.f;
#pragma unroll
            for (int j = 0; j < 8; ++j) {
                float dd = f0v[j] - fprev[o0 + j];
                d2 += dd * dd;
                float ee = f1v[j] - fprev[o0 + DD + j];
                d2 += ee * ee;
            }
#pragma unroll
            for (int off = 32; off > 0; off >>= 1) d2 += __shfl_xor(d2, off);
            if (lane == 0) atomicAdd(loss, d2);
        }
        if (!last) {
            float4 c0 = *(const float4*)(CgL + (size_t)b * DD + lane * 8);
            float4 c1 = *(const float4*)(CgL + (size_t)b * DD + lane * 8 + 4);
            float cg[8] = {c0.x, c0.y, c0.z, c0.w, c1.x, c1.y, c1.z, c1.w};
            float4 e0 = *(const float4*)(bu2 + lane * 8);
            float4 e1 = *(const float4*)(bu2 + lane * 8 + 4);
            float bv[8] = {e0.x, e0.y, e0.z, e0.w, e1.x, e1.y, e1.z, e1.w};
            float og0[8], og1[8], ou0[8], ou1[8];
#pragma unroll
            for (int j = 0; j < 8; ++j) {
                og0[j] = ag0[j] * inv0 + cg[j];
                og1[j] = ag1[j] * inv1 + cg[j];
                ou0[j] = au0[j] * inv0 + bv[j];
                ou1[j] = au1[j] * inv1 + bv[j];
            }
            *(float4*)(gpgO + o0) = float4{og0[0], og0[1], og0[2], og0[3]};
            *(float4*)(gpgO + o0 + 4) = float4{og0[4], og0[5], og0[6], og0[7]};
            *(float4*)(gpgO + o0 + DD) = float4{og1[0], og1[1], og1[2], og1[3]};
            *(float4*)(gpgO + o0 + DD + 4) = float4{og1[4], og1[5], og1[6], og1[7]};
            *(float4*)(gpuO + o0) = float4{ou0[0], ou0[1], ou0[2], ou0[3]};
            *(float4*)(gpuO + o0 + 4) = float4{ou0[4], ou0[5], ou0[6], ou0[7]};
            *(float4*)(gpuO + o0 + DD) = float4{ou1[0], ou1[1], ou1[2], ou1[3]};
            *(float4*)(gpuO + o0 + DD + 4) = float4{ou1[4], ou1[5], ou1[6], ou1[7]};
        }
    } else {
        // ---------------- q-part GEMM ----------------
        int tb = blockIdx.x - 192;
        int m0 = (tb >> 3) * 32, n0 = (tb & 7) * 64;
        // Phase 1: reconstruct q tile [32][512] -> LDS bf16-hi, XOR-swizzled.
        for (int j = 0; j < 8; ++j) {
            int e = j * 2048 + tid * 8;
            int row = e >> 9, col = e & 511;
            size_t o = (size_t)(m0 + row) * DD + col;
            float qv[8];
            recon8(o, qv);
            u16x8 hv;
#pragma unroll
            for (int jj = 0; jj < 8; ++jj) hv[jj] = bf16h(qv[jj]);
            int cslot = (col >> 3) & 7;
            int addr = row * 512 + (col & ~63) + ((cslot ^ (row & 7)) << 3);
            *(u16x8*)(sm + addr) = hv;
        }
        __syncthreads();
        f32x4 accg[2], accu[2];
#pragma unroll
        for (int i = 0; i < 2; ++i) { accg[i] = f32x4{0.f, 0.f, 0.f, 0.f}; accu[i] = f32x4{0.f, 0.f, 0.f, 0.f}; }
        int wv = tid >> 6, lane = tid & 63, lr = lane & 15, ls = lane >> 4;
        u16* wbuf = sm + 16384;
        auto stageW = [&](u16* buf, int k0) {
#pragma unroll
            for (int i2 = 0; i2 < 4; ++i2) {
                int aidx = tid + 256 * i2;
                int arr = aidx >> 9, jx = aidx & 511;
                int row = jx >> 3, sl = jx & 7;
                int ko = k0 + ((sl ^ (row & 7)) << 3);
                const u16* src = arr ? (Wuh + (size_t)(n0 + row) * 1024 + 512 + ko)
                                     : (Wgh + (size_t)(n0 + row) * 1536 + 512 + ko);
                gl_lds16(src, buf + arr * 4096 + jx * 8);
            }
        };
        stageW(wbuf, 0);
        __syncthreads();
        for (int t2 = 0; t2 < 8; ++t2) {
            u16* cur = wbuf + (t2 & 1) * 8192;
            if (t2 + 1 < 8) stageW(wbuf + ((t2 + 1) & 1) * 8192, (t2 + 1) * 64);
#pragma unroll
            for (int ks = 0; ks < 2; ++ks) {
                int slot = ks * 4 + ls;
                int n = 16 * wv + lr;
                int bo = n * 64 + ((slot ^ (n & 7)) << 3);
                bf16x8 gh8 = *(const bf16x8*)(cur + bo);
                bf16x8 uh8 = *(const bf16x8*)(cur + 4096 + bo);
#pragma unroll
                for (int rf = 0; rf < 2; ++rf) {
                    int r = 16 * rf + lr;
                    int ao = r * 512 + t2 * 64 + ((slot ^ (r & 7)) << 3);
                    bf16x8 ah8 = *(const bf16x8*)(sm + ao);
                    accg[rf] = mfma16(ah8, gh8, accg[rf]);
                    accu[rf] = mfma16(ah8, uh8, accu[rf]);
                }
            }
            __syncthreads();
        }
#pragma unroll
        for (int rf = 0; rf < 2; ++rf)
#pragma unroll
            for (int r = 0; r < 4; ++r) {
                int row = m0 + 16 * rf + 4 * ls + r;
                int col = n0 + 16 * wv + lr;
                size_t o = (size_t)row * DD + col;
                qgO[o] = accg[rf][r];
                quO[o] = accu[rf][r];
            }
    }
}

// ---------------------------------------------------------------------------
__global__ __launch_bounds__(256) void final_kernel(const float* __restrict__ fuse_last,
                                                    const float* __restrict__ ce,
                                                    const float* __restrict__ W_cls,
                                                    const float* __restrict__ b_cls,
                                                    const float* __restrict__ loss_acc,
                                                    float* __restrict__ out) {
    int b = blockIdx.x;
    int t = threadIdx.x;
    int w = t >> 6, lane = t & 63;
    __shared__ float invn[CC];
    __shared__ float img[CC];
    const float* fb = fuse_last + (size_t)b * CC * DD;
    for (int c = w; c < CC; c += 4) {
        const float* fr = fb + (size_t)c * DD + lane * 8;
        float4 a0 = *(const float4*)fr;
        float4 a1 = *(const float4*)(fr + 4);
        float ss = a0.x * a0.x + a0.y * a0.y + a0.z * a0.z + a0.w * a0.w +
                   a1.x * a1.x + a1.y * a1.y + a1.z * a1.z + a1.w * a1.w;
#pragma unroll
        for (int off = 32; off > 0; off >>= 1) ss += __shfl_xor(ss, off);
        if (lane == 0) invn[c] = 1.0f / fmaxf(sqrtf(ss), 1e-12f);
    }
    __syncthreads();
    for (int g = w; g < CC; g += 4) {
        int k = g / 6;
        const float* ar = ce + (size_t)g * DD + lane * 8;
        float4 c0 = *(const float4*)ar;
        float4 c1 = *(const float4*)(ar + 4);
        float av[8] = {c0.x, c0.y, c0.z, c0.w, c1.x, c1.y, c1.z, c1.w};
        float accp = 0.0f;
        for (int p = 0; p < 6; ++p) {
            int row = k * 6 + p;
            const float* fr = fb + (size_t)row * DD + lane * 8;
            float4 f0 = *(const float4*)fr;
            float4 f1 = *(const float4*)(fr + 4);
            float fv[8] = {f0.x, f0.y, f0.z, f0.w, f1.x, f1.y, f1.z, f1.w};
            float d = 0.0f;
#pragma unroll
            for (int j = 0; j < 8; ++j) d += fv[j] * av[j];
            accp += d * invn[row];
        }
#pragma unroll
        for (int off = 32; off > 0; off >>= 1) accp += __shfl_xor(accp, off);
        if (lane == 0) img[g] = accp * (100.0f / 6.0f);
    }
    __syncthreads();
    if (t < CC) out[BB * 7 + b * CC + t] = img[t];
    if (t < 7) {
        float sacc = b_cls[t];
        for (int c = 0; c < CC; ++c) sacc += img[c] * W_cls[t * CC + c];
        out[b * 7 + t] = sacc;
    }
    if (b == 0 && t == 0) out[BB * 7 + BB * CC] = loss_acc[0] * (1.0f / LOSS_DEN);
}

// ---------------------------------------------------------------------------
extern "C" void kernel_launch(void* const* d_in, const int* in_sizes, int n_in,
                              void* d_out, int out_size, void* d_ws, size_t ws_size,
                              hipStream_t stream) {
    const float* feats = (const float*)d_in[0];
    const float* ce = (const float*)d_in[1];
    const float* W_lin = (const float*)d_in[2];
    const float* b_lin = (const float*)d_in[3];
    const float* W_proj = (const float*)d_in[4];
    const float* W_gate = (const float*)d_in[5];
    const float* b_gate = (const float*)d_in[6];
    const float* W_upd = (const float*)d_in[7];
    const float* b_upd = (const float*)d_in[8];
    const float* W_cls = (const float*)d_in[9];
    const float* b_cls = (const float*)d_in[10];
    float* out = (float*)d_out;

    char* base = (char*)d_ws;
    size_t off = 0;
    auto alloc = [&](size_t bytes) -> char* {
        char* r = base + off;
        off += (bytes + 255) & ~(size_t)255;
        return r;
    };
    u16* Xh = (u16*)alloc((size_t)LL * BB * VV * DV * 2);
    u16* Xl = (u16*)alloc((size_t)LL * BB * VV * DV * 2);
    float* vtf = (float*)alloc((size_t)LL * BB * VV * DD * 4);
    float* VG = (float*)alloc((size_t)LL * BB * VV * DD * 4);
    float* VU = (float*)alloc((size_t)LL * BB * VV * DD * 4);
    float* ctx = (float*)alloc((size_t)LL * BB * DD * 4);
    float* Cg = (float*)alloc((size_t)LL * BB * DD * 4);
    float* fbuf0 = (float*)alloc((size_t)BB * CC * DD * 4);
    float* fbuf1 = (float*)alloc((size_t)BB * CC * DD * 4);
    float* gpg[2] = {(float*)alloc((size_t)BB * CC * DD * 4), (float*)alloc((size_t)BB * CC * DD * 4)};
    float* gpu[2] = {(float*)alloc((size_t)BB * CC * DD * 4), (float*)alloc((size_t)BB * CC * DD * 4)};
    float* qg[2] = {(float*)alloc((size_t)BB * CC * DD * 4), (float*)alloc((size_t)BB * CC * DD * 4)};
    float* qu[2] = {(float*)alloc((size_t)BB * CC * DD * 4), (float*)alloc((size_t)BB * CC * DD * 4)};
    float* loss = (float*)alloc(256);
    u16* Wlh = (u16*)alloc((size_t)NLW * 2);
    u16* Wll = (u16*)alloc((size_t)NLW * 2);
    u16* Wgh = (u16*)alloc((size_t)NGW * 2);
    u16* Wuh = (u16*)alloc((size_t)NUW * 2);
    u16* Wcg = (u16*)alloc((size_t)512 * DV * 2);
    u16* Wcu = (u16*)alloc((size_t)512 * DV * 2);
    float* bg2 = (float*)alloc(512 * 4);
    float* bu2 = (float*)alloc(512 * 4);
    u16* qah = (u16*)alloc((size_t)BB * CC * DD * 2);
    u16* qal = (u16*)alloc((size_t)BB * CC * DD * 2);
    u16* qbh = (u16*)alloc((size_t)BB * CC * DD * 2);
    u16* qbl = (u16*)alloc((size_t)BB * CC * DD * 2);
    u16* qPh[2] = {qah, qbh};
    u16* qPl[2] = {qal, qbl};

    // ---- precompute (2 launches) ----
    int total_pre = CTX_BLKS + 2 * WCOMB_BLKS + BIAS_BLKS + POOL2_BLKS + WSPLIT4_BLKS + INITQ8_BLKS;
    mega_pre<<<total_pre, 256, 0, stream>>>(feats, W_lin, W_gate, W_upd, W_proj,
                                            b_lin, b_gate, b_upd, ce,
                                            Xh, Xl, Wlh, Wll, Wgh, Wuh, Wcg, Wcu,
                                            bg2, bu2, qah, qal, loss, ctx);
    big_gemm<<<3576, 256, 0, stream>>>(Xh, Xl, Wlh, Wll, b_lin, vtf, Wcg, Wcu, VG, VU,
                                       ctx, W_gate, bg2, Cg);

    // ---- 12-layer scan: ONE launch per layer ----
    for (int l = 0; l < LL; ++l) {
        float* fcur = (l & 1) ? fbuf1 : fbuf0;
        const float* fprev = (l & 1) ? fbuf0 : fbuf1;
        int last = (l == LL - 1) ? 1 : 0;
        int first = (l == 0) ? 1 : 0;
        int rd = (l + 1) & 1;  // prev-set index (for l==0 unused)
        int wr2 = l & 1;
        size_t loff = (size_t)l * BB * VV * DD;
        layer_step<<<last ? 192 : 576, 256, 0, stream>>>(
            qPh[l & 1], qPl[l & 1],
            gpg[rd], gpu[rd], qg[rd], qu[rd],
            vtf + loff, VG + loff, VU + loff,
            Cg + (size_t)l * BB * DD, bu2,
            fcur, fprev, loss, l > 0 ? 1 : 0, first, last,
            qPh[(l + 1) & 1], qPl[(l + 1) & 1],
            gpg[wr2], gpu[wr2], Wgh, Wuh, qg[wr2], qu[wr2]);
    }

    final_kernel<<<BB, 256, 0, stream>>>((LL - 1) & 1 ? fbuf1 : fbuf0, ce, W_cls, b_cls, loss, out);
}

// Round 14
// 790.352 us; speedup vs baseline: 1.3018x; 1.3018x over previous
//
#include <hip/hip_runtime.h>
#include <hip/hip_bf16.h>

#define LL 12
#define BB 32
#define SS 197
#define DV 768
#define DD 512
#define CC 48
#define VV 49
#define LOSS_DEN 786432.0f

typedef unsigned short u16;
typedef unsigned int u32;
using bf16x8 = __attribute__((ext_vector_type(8))) __bf16;
using f32x4 = __attribute__((ext_vector_type(4))) float;
using u16x8 = __attribute__((ext_vector_type(8))) u16;
using u16x4 = __attribute__((ext_vector_type(4))) u16;

__device__ __forceinline__ u16 bf16h(float x) {
    u32 u = __builtin_bit_cast(u32, x);
    return (u16)((u + 0x7FFFu + ((u >> 16) & 1u)) >> 16);
}
__device__ __forceinline__ float bf2f(u16 h) {
    u32 u = ((u32)h) << 16;
    return __builtin_bit_cast(float, u);
}
__device__ __forceinline__ f32x4 mfma16(bf16x8 a, bf16x8 b, f32x4 c) {
    return __builtin_amdgcn_mfma_f32_16x16x32_bf16(a, b, c, 0, 0, 0);
}
__device__ __forceinline__ void gl_lds16(const void* g, void* s) {
    __builtin_amdgcn_global_load_lds((const __attribute__((address_space(1))) u32*)g,
                                     (__attribute__((address_space(3))) u32*)s, 16, 0, 0);
}

#define NLW (512 * 768)
#define NGW (512 * 1536)
#define NUW (512 * 1024)
#define CTX_BLKS 48                               // (384/64) x (512/64)
#define POOL2_BLKS (LL * BB * 2)                  // 768
#define WSPLIT4_BLKS ((NLW + NGW + NUW) / 1024)   // 1664
#define INITQ8_BLKS ((BB * CC * DD) / 2048)       // 384

// ---------------------------------------------------------------------------
// f32 64x64-tile GEMM body (NT): C[m,n] = sum_k A[m,k]*W[n*wstride+k] + bias[n]
__device__ __forceinline__ void gemm_f32_tile(const float* __restrict__ A, int lda,
                                              const float* __restrict__ W, int wstride, int K,
                                              const float* __restrict__ bias,
                                              float* __restrict__ Cout,
                                              int m0, int n0, int t, float* AsB, float* BsB) {
    float (*As)[65] = (float(*)[65])AsB;
    float (*Bs)[65] = (float(*)[65])BsB;
    int r = t >> 2;
    int kc = (t & 3) * 8;
    int tx = t & 15, ty = t >> 4;
    float acc[4][4] = {};
    for (int k0 = 0; k0 < K; k0 += 32) {
        const float4* pa = (const float4*)(A + (size_t)(m0 + r) * lda + k0 + kc);
        float4 a0 = pa[0], a1 = pa[1];
        const float4* pw = (const float4*)(W + (size_t)(n0 + r) * wstride + k0 + kc);
        float4 w0 = pw[0], w1 = pw[1];
        As[kc + 0][r] = a0.x; As[kc + 1][r] = a0.y; As[kc + 2][r] = a0.z; As[kc + 3][r] = a0.w;
        As[kc + 4][r] = a1.x; As[kc + 5][r] = a1.y; As[kc + 6][r] = a1.z; As[kc + 7][r] = a1.w;
        Bs[kc + 0][r] = w0.x; Bs[kc + 1][r] = w0.y; Bs[kc + 2][r] = w0.z; Bs[kc + 3][r] = w0.w;
        Bs[kc + 4][r] = w1.x; Bs[kc + 5][r] = w1.y; Bs[kc + 6][r] = w1.z; Bs[kc + 7][r] = w1.w;
        __syncthreads();
#pragma unroll
        for (int kk = 0; kk < 32; ++kk) {
            float a[4], b[4];
#pragma unroll
            for (int i = 0; i < 4; ++i) { a[i] = As[kk][ty * 4 + i]; b[i] = Bs[kk][tx * 4 + i]; }
#pragma unroll
            for (int i = 0; i < 4; ++i)
#pragma unroll
                for (int j = 0; j < 4; ++j) acc[i][j] += a[i] * b[j];
        }
        __syncthreads();
    }
#pragma unroll
    for (int i = 0; i < 4; ++i) {
        int m = m0 + ty * 4 + i;
#pragma unroll
        for (int j = 0; j < 4; ++j) {
            int n = n0 + tx * 4 + j;
            Cout[(size_t)m * DD + n] = acc[i][j] + (bias ? bias[n] : 0.0f);
        }
    }
}

// ---------------------------------------------------------------------------
// Merged precompute: ctx GEMM (first) | pool+split X | weight splits | init q
__global__ __launch_bounds__(256) void mega_pre(const float* __restrict__ feats,
                                                const float* __restrict__ Wl,
                                                const float* __restrict__ Wg,
                                                const float* __restrict__ Wu,
                                                const float* __restrict__ Wp,
                                                const float* __restrict__ ce,
                                                u16* __restrict__ Xh, u16* __restrict__ Xl,
                                                u16* Wlh, u16* Wll, u16* Wgh, u16* Wuh,
                                                u16* __restrict__ qh, u16* __restrict__ ql,
                                                float* __restrict__ loss,
                                                float* __restrict__ ctx) {
    __shared__ float smf[2 * 32 * 65];
    int bid = blockIdx.x;
    int t = threadIdx.x;
    if (bid < CTX_BLKS) {
        gemm_f32_tile(feats, SS * DV, Wp, DV, DV, nullptr, ctx,
                      (bid >> 3) * 64, (bid & 7) * 64, t, smf, smf + 32 * 65);
    } else if (bid < CTX_BLKS + POOL2_BLKS) {
        if (t >= 192) return;
        int pb = bid - CTX_BLKS;
        int lb = pb >> 1, half = pb & 1;
        const float4* fb = (const float4*)(feats + (size_t)lb * SS * DV);  // 192 quads/row
        size_t xbase = (size_t)lb * VV * DV + 4 * t;
        if (half == 0) {
            float4 c = fb[t];
            float cv[4] = {c.x, c.y, c.z, c.w};
            u16x4 hh, ll2;
#pragma unroll
            for (int j = 0; j < 4; ++j) {
                u16 h = bf16h(cv[j]);
                hh[j] = h;
                ll2[j] = bf16h(cv[j] - bf2f(h));
            }
            *(u16x4*)(Xh + xbase) = hh;
            *(u16x4*)(Xl + xbase) = ll2;
        }
        int ib0 = half * 24, ib1 = ib0 + 24;
        for (int i = ib0; i < ib1; ++i) {
            int s = (i * 196) / 48;
            int e = ((i + 1) * 196 + 47) / 48;
            float4 acc = {0.f, 0.f, 0.f, 0.f};
            for (int j = s; j < e; ++j) {
                float4 v = fb[(size_t)(1 + j) * 192 + t];
                acc.x += v.x; acc.y += v.y; acc.z += v.z; acc.w += v.w;
            }
            float inv = 1.0f / (float)(e - s);
            float av[4] = {acc.x * inv, acc.y * inv, acc.z * inv, acc.w * inv};
            u16x4 hh, ll2;
#pragma unroll
            for (int j = 0; j < 4; ++j) {
                u16 h = bf16h(av[j]);
                hh[j] = h;
                ll2[j] = bf16h(av[j] - bf2f(h));
            }
            size_t o = xbase + (size_t)(1 + i) * DV;
            *(u16x4*)(Xh + o) = hh;
            *(u16x4*)(Xl + o) = ll2;
        }
    } else if (bid < CTX_BLKS + POOL2_BLKS + WSPLIT4_BLKS) {
        int i = ((bid - CTX_BLKS - POOL2_BLKS) * 256 + t) * 4;
        float4 v;
        u16 *ph, *pl = nullptr;
        int j;
        if (i < NLW) { v = *(const float4*)(Wl + i); ph = Wlh; pl = Wll; j = i; }
        else if (i < NLW + NGW) { j = i - NLW; v = *(const float4*)(Wg + j); ph = Wgh; }
        else { j = i - NLW - NGW; v = *(const float4*)(Wu + j); ph = Wuh; }
        float vv[4] = {v.x, v.y, v.z, v.w};
        u16x4 hh, ll2;
#pragma unroll
        for (int k = 0; k < 4; ++k) {
            u16 h = bf16h(vv[k]);
            hh[k] = h;
            ll2[k] = bf16h(vv[k] - bf2f(h));
        }
        *(u16x4*)(ph + j) = hh;
        if (pl) *(u16x4*)(pl + j) = ll2;
    } else {
        int i8 = ((bid - CTX_BLKS - POOL2_BLKS - WSPLIT4_BLKS) * 256 + t) * 8;
        int src = i8 % (CC * DD);
        float4 a = *(const float4*)(ce + src);
        float4 b2 = *(const float4*)(ce + src + 4);
        float vv[8] = {a.x, a.y, a.z, a.w, b2.x, b2.y, b2.z, b2.w};
        u16x8 hh, ll2;
#pragma unroll
        for (int k = 0; k < 8; ++k) {
            u16 h = bf16h(vv[k]);
            hh[k] = h;
            ll2[k] = bf16h(vv[k] - bf2f(h));
        }
        *(u16x8*)(qh + i8) = hh;
        *(u16x8*)(ql + i8) = ll2;
        if (i8 == 0) loss[0] = 0.0f;
    }
}

// ---------------------------------------------------------------------------
// vt = X @ W_lin.T + b_lin (bf16x3 MFMA, XCD-localized), f32 output.
// bids >= 1176: Cg f32 GEMM.
__global__ __launch_bounds__(256, 2) void vt_gemm(const u16* __restrict__ Xh, const u16* __restrict__ Xl,
                                                  const u16* __restrict__ Wh, const u16* __restrict__ Wl,
                                                  const float* __restrict__ bias,
                                                  float* __restrict__ vtf,
                                                  const float* __restrict__ ctx,
                                                  const float* __restrict__ Wg,
                                                  const float* __restrict__ bg,
                                                  float* __restrict__ Cg) {
    __shared__ u16 sm[24576];
    int tid = threadIdx.x;
    if (blockIdx.x >= 1176) {
        int b2 = blockIdx.x - 1176;
        gemm_f32_tile(ctx, DD, Wg + 1024, 1536, DD, bg, Cg,
                      (b2 >> 3) * 64, (b2 & 7) * 64, tid, (float*)sm, (float*)sm + 32 * 65);
        return;
    }
    int w = tid >> 6, l = tid & 63, lr = l & 15, ls = l >> 4;
    int i = blockIdx.x, m, n;
    if (i < 1152) { int a = i >> 6, r2 = i & 63; m = 8 * a + (r2 & 7); n = r2 >> 3; }
    else { int j = i - 1152; m = 144 + (j >> 3); n = j & 7; }
    int m0 = m * 128, n0 = n * 64;
    f32x4 acc[2][4];
#pragma unroll
    for (int ii = 0; ii < 2; ++ii)
#pragma unroll
        for (int j = 0; j < 4; ++j) acc[ii][j] = f32x4{0.f, 0.f, 0.f, 0.f};

    auto stage = [&](u16* dst, int k0) {
#pragma unroll
        for (int is = 0; is < 6; ++is) {
            int q = is * 256 + tid;
            const u16* src;
            int off;
            if (is < 2)      { int qr = q;        int row = qr >> 2, sl = qr & 3; src = Xh + (size_t)(m0 + row) * DV + k0 + ((sl ^ ((row >> 1) & 3)) << 3); off = qr * 8; }
            else if (is < 4) { int qr = q - 512;  int row = qr >> 2, sl = qr & 3; src = Xl + (size_t)(m0 + row) * DV + k0 + ((sl ^ ((row >> 1) & 3)) << 3); off = 4096 + qr * 8; }
            else if (is < 5) { int qr = q - 1024; int row = qr >> 2, sl = qr & 3; src = Wh + (size_t)(n0 + row) * DV + k0 + ((sl ^ ((row >> 1) & 3)) << 3); off = 8192 + qr * 8; }
            else             { int qr = q - 1280; int row = qr >> 2, sl = qr & 3; src = Wl + (size_t)(n0 + row) * DV + k0 + ((sl ^ ((row >> 1) & 3)) << 3); off = 10240 + qr * 8; }
            gl_lds16(src, dst + off);
        }
    };

    stage(sm, 0);
    __syncthreads();
    for (int t = 0; t < 24; ++t) {
        u16* cur = sm + ((t & 1) ? 12288 : 0);
        u16* nxt = sm + ((t & 1) ? 0 : 12288);
        if (t + 1 < 24) stage(nxt, (t + 1) * 32);
        bf16x8 ah[2], al2[2], bh[4], bl2[4];
#pragma unroll
        for (int rf = 0; rf < 2; ++rf) {
            int row = 32 * w + 16 * rf + lr;
            int ro = row * 32 + ((ls ^ ((row >> 1) & 3)) << 3);
            ah[rf] = *(const bf16x8*)(cur + ro);
            al2[rf] = *(const bf16x8*)(cur + 4096 + ro);
        }
#pragma unroll
        for (int cf = 0; cf < 4; ++cf) {
            int nn = 16 * cf + lr;
            int no = nn * 32 + ((ls ^ ((nn >> 1) & 3)) << 3);
            bh[cf] = *(const bf16x8*)(cur + 8192 + no);
            bl2[cf] = *(const bf16x8*)(cur + 10240 + no);
        }
#pragma unroll
        for (int rf = 0; rf < 2; ++rf)
#pragma unroll
            for (int cf = 0; cf < 4; ++cf) {
                acc[rf][cf] = mfma16(ah[rf], bh[cf], acc[rf][cf]);
                acc[rf][cf] = mfma16(ah[rf], bl2[cf], acc[rf][cf]);
                acc[rf][cf] = mfma16(al2[rf], bh[cf], acc[rf][cf]);
            }
        __syncthreads();
    }
#pragma unroll
    for (int rf = 0; rf < 2; ++rf)
#pragma unroll
        for (int cf = 0; cf < 4; ++cf)
#pragma unroll
            for (int r = 0; r < 4; ++r) {
                int row = m0 + 32 * w + 16 * rf + 4 * ls + r;
                int col = n0 + 16 * cf + lr;
                vtf[(size_t)row * DD + col] = acc[rf][cf][r] + bias[col];
            }
}

// ---------------------------------------------------------------------------
// 32x64-tile x1 gate/upd GEMM core: acc = Ah·Wh. K=512 (8 x BK=64), dbuf.
// Buffer: Ah [0,2048), Wg [2048,6144), Wu [6144,10240); dbuf = 40 KB total.
__device__ __forceinline__ void gemm32x64(u16* sm, const u16* Ah,
                                          const u16* Wgh, const u16* Wuh,
                                          int m0, int n0, int tid,
                                          f32x4 accg[2], f32x4 accu[2]) {
    int w = tid >> 6, lane = tid & 63, lr = lane & 15, ls = lane >> 4;
    auto stage = [&](u16* buf, int k0) {
        {
            int j = tid, row = j >> 3, sl = j & 7;
            int ko = k0 + ((sl ^ (row & 7)) << 3);
            gl_lds16(Ah + (size_t)(m0 + row) * DD + ko, buf + j * 8);
        }
#pragma unroll
        for (int i2 = 0; i2 < 4; ++i2) {
            int aidx = tid + 256 * i2;
            int arr = aidx >> 9, j = aidx & 511;
            int row = j >> 3, sl = j & 7;
            int ko = k0 + ((sl ^ (row & 7)) << 3);
            const u16* src = arr ? (Wuh + (size_t)(n0 + row) * 1024 + ko)
                                 : (Wgh + (size_t)(n0 + row) * 1536 + ko);
            gl_lds16(src, buf + 2048 + arr * 4096 + j * 8);
        }
    };
    stage(sm, 0);
    __syncthreads();
    for (int t = 0; t < 8; ++t) {
        u16* cur = sm + (t & 1) * 10240;
        if (t + 1 < 8) stage(sm + ((t + 1) & 1) * 10240, (t + 1) * 64);
#pragma unroll
        for (int ks = 0; ks < 2; ++ks) {
            int slot = ks * 4 + ls;
            int n = 16 * w + lr;
            int bo = n * 64 + ((slot ^ (n & 7)) << 3);
            bf16x8 gh8 = *(const bf16x8*)(cur + 2048 + bo);
            bf16x8 uh8 = *(const bf16x8*)(cur + 6144 + bo);
#pragma unroll
            for (int rf = 0; rf < 2; ++rf) {
                int r = 16 * rf + lr;
                int ao = r * 64 + ((slot ^ (r & 7)) << 3);
                bf16x8 ah8 = *(const bf16x8*)(cur + ao);
                accg[rf] = mfma16(ah8, gh8, accg[rf]);
                accu[rf] = mfma16(ah8, uh8, accu[rf]);
            }
        }
        __syncthreads();
    }
}

// ---------------------------------------------------------------------------
// blocks 0..191: attention (f32 vt); 192..575: q-part GEMM x1.
__global__ __launch_bounds__(256, 4) void attn_qpart(
    const u16* __restrict__ qh, const u16* __restrict__ ql,
    const float* __restrict__ vtL,
    float* __restrict__ fcur, const float* __restrict__ fprev,
    u16* __restrict__ fh,
    float* __restrict__ loss, int do_loss,
    const u16* __restrict__ Wgh, const u16* __restrict__ Wuh,
    float* __restrict__ qg, float* __restrict__ qu) {
    __shared__ u16 sm[20480];
    int tid = threadIdx.x;
    if (blockIdx.x < 192) {
        // ---------------- attention ----------------
        int wgid = blockIdx.x * 4 + (tid >> 6);
        int lane = tid & 63;
        int b = wgid / 24;
        int r0 = b * CC + (wgid % 24) * 2;
        size_t o0 = (size_t)r0 * DD + lane * 8;
        u16x8 h0 = *(const u16x8*)(qh + o0), g0 = *(const u16x8*)(ql + o0);
        u16x8 h1 = *(const u16x8*)(qh + o0 + DD), g1 = *(const u16x8*)(ql + o0 + DD);
        float q0v[8], q1v[8];
#pragma unroll
        for (int j = 0; j < 8; ++j) {
            q0v[j] = bf2f(h0[j]) + bf2f(g0[j]);
            q1v[j] = bf2f(h1[j]) + bf2f(g1[j]);
        }
        const float* vf = vtL + (size_t)b * VV * DD + lane * 8;
        float m0 = -3e38f, m1 = -3e38f, s0 = 0.f, s1 = 0.f;
        float a0[8] = {}, a1[8] = {};
        for (int v = 0; v < VV; ++v) {
            float4 r0v = *(const float4*)(vf + (size_t)v * DD);
            float4 r1v = *(const float4*)(vf + (size_t)v * DD + 4);
            float rv[8] = {r0v.x, r0v.y, r0v.z, r0v.w, r1v.x, r1v.y, r1v.z, r1v.w};
            float p0 = 0.f, p1 = 0.f;
#pragma unroll
            for (int j = 0; j < 8; ++j) { p0 += q0v[j] * rv[j]; p1 += q1v[j] * rv[j]; }
#pragma unroll
            for (int off = 32; off > 0; off >>= 1) { p0 += __shfl_xor(p0, off); p1 += __shfl_xor(p1, off); }
            float nm0 = fmaxf(m0, p0);
            float sc0 = __expf(m0 - nm0), w0 = __expf(p0 - nm0);
            s0 = s0 * sc0 + w0;
            float nm1 = fmaxf(m1, p1);
            float sc1 = __expf(m1 - nm1), w1 = __expf(p1 - nm1);
            s1 = s1 * sc1 + w1;
#pragma unroll
            for (int j = 0; j < 8; ++j) {
                a0[j] = a0[j] * sc0 + w0 * rv[j];
                a1[j] = a1[j] * sc1 + w1 * rv[j];
            }
            m0 = nm0;
            m1 = nm1;
        }
        float inv0 = 1.0f / s0, inv1 = 1.0f / s1;
        float d2 = 0.f;
        float f0v[8], f1v[8];
        u16x8 oh0, oh1;
#pragma unroll
        for (int j = 0; j < 8; ++j) {
            float f = a0[j] * inv0;
            f0v[j] = f;
            oh0[j] = bf16h(f);
            float f2 = a1[j] * inv1;
            f1v[j] = f2;
            oh1[j] = bf16h(f2);
        }
        *(float4*)(fcur + o0) = float4{f0v[0], f0v[1], f0v[2], f0v[3]};
        *(float4*)(fcur + o0 + 4) = float4{f0v[4], f0v[5], f0v[6], f0v[7]};
        *(float4*)(fcur + o0 + DD) = float4{f1v[0], f1v[1], f1v[2], f1v[3]};
        *(float4*)(fcur + o0 + DD + 4) = float4{f1v[4], f1v[5], f1v[6], f1v[7]};
        *(u16x8*)(fh + o0) = oh0;
        *(u16x8*)(fh + o0 + DD) = oh1;
        if (do_loss) {
#pragma unroll
            for (int j = 0; j < 8; ++j) {
                float d = f0v[j] - fprev[o0 + j];
                d2 += d * d;
                float e = f1v[j] - fprev[o0 + DD + j];
                d2 += e * e;
            }
#pragma unroll
            for (int off = 32; off > 0; off >>= 1) d2 += __shfl_xor(d2, off);
            if (lane == 0) atomicAdd(loss, d2);
        }
    } else {
        // ---------------- q-part GEMM (32x64 tile, K=512, x1) ----------------
        int tb = blockIdx.x - 192;
        int m0 = (tb >> 3) * 32, n0 = (tb & 7) * 64;
        f32x4 accg[2], accu[2];
#pragma unroll
        for (int i = 0; i < 2; ++i) { accg[i] = f32x4{0.f, 0.f, 0.f, 0.f}; accu[i] = f32x4{0.f, 0.f, 0.f, 0.f}; }
        gemm32x64(sm, qh, Wgh + 512, Wuh + 512, m0, n0, tid, accg, accu);
        int w = tid >> 6, lane = tid & 63, lr = lane & 15, ls = lane >> 4;
#pragma unroll
        for (int rf = 0; rf < 2; ++rf)
#pragma unroll
            for (int r = 0; r < 4; ++r) {
                int row = m0 + 16 * rf + 4 * ls + r;
                int col = n0 + 16 * w + lr;
                size_t o = (size_t)row * DD + col;
                qg[o] = accg[rf][r];
                qu[o] = accu[rf][r];
            }
    }
}

// ---------------------------------------------------------------------------
// fuse-part GEMM (32x64 tile, K=512, x1) + combine + q update.
__global__ __launch_bounds__(256, 4) void fusepart(
    const u16* __restrict__ fhp,
    const u16* __restrict__ qhp, const u16* __restrict__ qlp,
    const u16* __restrict__ Wgh, const u16* __restrict__ Wuh,
    const float* __restrict__ qg, const float* __restrict__ qu,
    const float* __restrict__ CgL, const float* __restrict__ bu,
    u16* __restrict__ qoh, u16* __restrict__ qol) {
    __shared__ u16 sm[20480];
    int tid = threadIdx.x;
    int m0 = (blockIdx.x >> 3) * 32, n0 = (blockIdx.x & 7) * 64;
    f32x4 accg[2], accu[2];
#pragma unroll
    for (int i = 0; i < 2; ++i) { accg[i] = f32x4{0.f, 0.f, 0.f, 0.f}; accu[i] = f32x4{0.f, 0.f, 0.f, 0.f}; }
    gemm32x64(sm, fhp, Wgh, Wuh, m0, n0, tid, accg, accu);
    int w = tid >> 6, lane = tid & 63, lr = lane & 15, ls = lane >> 4;
#pragma unroll
    for (int rf = 0; rf < 2; ++rf)
#pragma unroll
        for (int r = 0; r < 4; ++r) {
            int row = m0 + 16 * rf + 4 * ls + r;
            int col = n0 + 16 * w + lr;
            int b = row / CC;
            size_t o = (size_t)row * DD + col;
            float gpre = accg[rf][r] + qg[o] + CgL[(size_t)b * DD + col];
            float upre = accu[rf][r] + qu[o] + bu[col];
            float g = 1.0f / (1.0f + __expf(-gpre));
            float u = tanhf(upre);
            float qv = bf2f(qhp[o]) + bf2f(qlp[o]);
            float qo = g * qv + (1.0f - g) * u;
            u16 hh = bf16h(qo);
            qoh[o] = hh;
            qol[o] = bf16h(qo - bf2f(hh));
        }
}

// ---------------------------------------------------------------------------
__global__ __launch_bounds__(256) void final_kernel(const float* __restrict__ fuse_last,
                                                    const float* __restrict__ ce,
                                                    const float* __restrict__ W_cls,
                                                    const float* __restrict__ b_cls,
                                                    const float* __restrict__ loss_acc,
                                                    float* __restrict__ out) {
    int b = blockIdx.x;
    int t = threadIdx.x;
    int w = t >> 6, lane = t & 63;
    __shared__ float invn[CC];
    __shared__ float img[CC];
    const float* fb = fuse_last + (size_t)b * CC * DD;
    for (int c = w; c < CC; c += 4) {
        const float* fr = fb + (size_t)c * DD + lane * 8;
        float4 a0 = *(const float4*)fr;
        float4 a1 = *(const float4*)(fr + 4);
        float ss = a0.x * a0.x + a0.y * a0.y + a0.z * a0.z + a0.w * a0.w +
                   a1.x * a1.x + a1.y * a1.y + a1.z * a1.z + a1.w * a1.w;
#pragma unroll
        for (int off = 32; off > 0; off >>= 1) ss += __shfl_xor(ss, off);
        if (lane == 0) invn[c] = 1.0f / fmaxf(sqrtf(ss), 1e-12f);
    }
    __syncthreads();
    for (int g = w; g < CC; g += 4) {
        int k = g / 6;
        const float* ar = ce + (size_t)g * DD + lane * 8;
        float4 c0 = *(const float4*)ar;
        float4 c1 = *(const float4*)(ar + 4);
        float av[8] = {c0.x, c0.y, c0.z, c0.w, c1.x, c1.y, c1.z, c1.w};
        float accp = 0.0f;
        for (int p = 0; p < 6; ++p) {
            int row = k * 6 + p;
            const float* fr = fb + (size_t)row * DD + lane * 8;
            float4 f0 = *(const float4*)fr;
            float4 f1 = *(const float4*)(fr + 4);
            float fv[8] = {f0.x, f0.y, f0.z, f0.w, f1.x, f1.y, f1.z, f1.w};
            float d = 0.0f;
#pragma unroll
            for (int j = 0; j < 8; ++j) d += fv[j] * av[j];
            accp += d * invn[row];
        }
#pragma unroll
        for (int off = 32; off > 0; off >>= 1) accp += __shfl_xor(accp, off);
        if (lane == 0) img[g] = accp * (100.0f / 6.0f);
    }
    __syncthreads();
    if (t < CC) out[BB * 7 + b * CC + t] = img[t];
    if (t < 7) {
        float sacc = b_cls[t];
        for (int c = 0; c < CC; ++c) sacc += img[c] * W_cls[t * CC + c];
        out[b * 7 + t] = sacc;
    }
    if (b == 0 && t == 0) out[BB * 7 + BB * CC] = loss_acc[0] * (1.0f / LOSS_DEN);
}

// ---------------------------------------------------------------------------
extern "C" void kernel_launch(void* const* d_in, const int* in_sizes, int n_in,
                              void* d_out, int out_size, void* d_ws, size_t ws_size,
                              hipStream_t stream) {
    const float* feats = (const float*)d_in[0];
    const float* ce = (const float*)d_in[1];
    const float* W_lin = (const float*)d_in[2];
    const float* b_lin = (const float*)d_in[3];
    const float* W_proj = (const float*)d_in[4];
    const float* W_gate = (const float*)d_in[5];
    const float* b_gate = (const float*)d_in[6];
    const float* W_upd = (const float*)d_in[7];
    const float* b_upd = (const float*)d_in[8];
    const float* W_cls = (const float*)d_in[9];
    const float* b_cls = (const float*)d_in[10];
    float* out = (float*)d_out;

    char* base = (char*)d_ws;
    size_t off = 0;
    auto alloc = [&](size_t bytes) -> char* {
        char* r = base + off;
        off += (bytes + 255) & ~(size_t)255;
        return r;
    };
    u16* Xh = (u16*)alloc((size_t)LL * BB * VV * DV * 2);
    u16* Xl = (u16*)alloc((size_t)LL * BB * VV * DV * 2);
    float* vtf = (float*)alloc((size_t)LL * BB * VV * DD * 4);
    float* ctx = (float*)alloc((size_t)LL * BB * DD * 4);
    float* Cg = (float*)alloc((size_t)LL * BB * DD * 4);
    float* fbuf0 = (float*)alloc((size_t)BB * CC * DD * 4);
    float* fbuf1 = (float*)alloc((size_t)BB * CC * DD * 4);
    float* qg = (float*)alloc((size_t)BB * CC * DD * 4);
    float* qu = (float*)alloc((size_t)BB * CC * DD * 4);
    float* loss = (float*)alloc(256);
    u16* Wlh = (u16*)alloc((size_t)NLW * 2);
    u16* Wll = (u16*)alloc((size_t)NLW * 2);
    u16* Wgh = (u16*)alloc((size_t)NGW * 2);
    u16* Wuh = (u16*)alloc((size_t)NUW * 2);
    u16* fh = (u16*)alloc((size_t)BB * CC * DD * 2);
    u16* qah = (u16*)alloc((size_t)BB * CC * DD * 2);
    u16* qal = (u16*)alloc((size_t)BB * CC * DD * 2);
    u16* qbh = (u16*)alloc((size_t)BB * CC * DD * 2);
    u16* qbl = (u16*)alloc((size_t)BB * CC * DD * 2);
    u16* qph[2] = {qah, qbh};
    u16* qpl[2] = {qal, qbl};

    // ---- precompute (2 launches) ----
    mega_pre<<<CTX_BLKS + POOL2_BLKS + WSPLIT4_BLKS + INITQ8_BLKS, 256, 0, stream>>>(
        feats, W_lin, W_gate, W_upd, W_proj, ce, Xh, Xl, Wlh, Wll, Wgh, Wuh,
        qah, qal, loss, ctx);
    vt_gemm<<<1176 + CTX_BLKS, 256, 0, stream>>>(Xh, Xl, Wlh, Wll, b_lin, vtf,
                                                 ctx, W_gate, b_gate, Cg);

    // ---- 12-layer scan ----
    int qc = 0;
    for (int l = 0; l < LL; ++l) {
        float* fcur = (l & 1) ? fbuf1 : fbuf0;
        const float* fprev = (l & 1) ? fbuf0 : fbuf1;
        int grid = (l < LL - 1) ? 576 : 192;
        attn_qpart<<<grid, 256, 0, stream>>>(qph[qc], qpl[qc],
                                             vtf + (size_t)l * BB * VV * DD,
                                             fcur, fprev, fh, loss, l > 0 ? 1 : 0,
                                             Wgh, Wuh, qg, qu);
        if (l < LL - 1) {
            fusepart<<<384, 256, 0, stream>>>(fh, qph[qc], qpl[qc],
                                              Wgh, Wuh, qg, qu,
                                              Cg + (size_t)l * BB * DD, b_upd,
                                              qph[qc ^ 1], qpl[qc ^ 1]);
            qc ^= 1;
        }
    }

    final_kernel<<<BB, 256, 0, stream>>>((LL - 1) & 1 ? fbuf1 : fbuf0, ce, W_cls, b_cls, loss, out);
}